// Round 3
// baseline (51.254 us; speedup 1.0000x reference)
//
#include <hip/hip_runtime.h>
#include <hip/hip_bf16.h>

#define NOBJ 25
#define D0 256

typedef short bf16x8 __attribute__((ext_vector_type(8)));
typedef short s16x4 __attribute__((ext_vector_type(4)));
typedef float f32x4 __attribute__((ext_vector_type(4)));

__device__ __forceinline__ short f2bf(float f) {
  __hip_bfloat16 b = __float2bfloat16(f);  // RTN
  return *reinterpret_cast<short*>(&b);
}
__device__ __forceinline__ float bf2f(short s) {
  unsigned u = ((unsigned)(unsigned short)s) << 16;
  return __uint_as_float(u);
}

// ---------------------------------------------------------------------------
// prep: (a) conv taps -> bf16 (2,256,64); (b) MLP weights -> hi/lo bf16 in
// fragment-linear layout so mlp's B-frag loads are coalesced dwordx4.
// idx(term,nt,ks,lane,j): value = w[nt*16+(lane&15)][ks*32+(lane>>4)*8+j].
// L1: 131072 shorts @0, L2: @131072, L3 (10 cols, zero-padded to 16): @262144.
// ---------------------------------------------------------------------------
__global__ __launch_bounds__(256) void prep_kernel(
    const float* __restrict__ cw0, const float* __restrict__ cw1,
    const float* __restrict__ w1, const float* __restrict__ w2,
    const float* __restrict__ w3,
    short* __restrict__ wbc, short* __restrict__ wfm) {
  int i = blockIdx.x * 256 + threadIdx.x;
  if (i < 32768) {
    float v = (i < 16384) ? cw0[i] : cw1[i - 16384];
    wbc[i] = f2bf(v);
    return;
  }
  i -= 32768;  // 0 .. 270335
  const float* w; int NT, base;
  if (i < 131072)      { w = w1; NT = 16; base = 0; }
  else if (i < 262144) { w = w2; NT = 16; base = 131072; }
  else                 { w = w3; NT = 1;  base = 262144; }
  const int idx = i - base;
  const int per_term = NT * 4096;
  const int term = idx / per_term;
  const int f = idx % per_term;
  const int nt = f >> 12;
  const int ks = (f >> 9) & 7;
  const int l  = (f >> 3) & 63;
  const int j  = f & 7;
  const int col = nt * 16 + (l & 15);
  const int k   = ks * 32 + (l >> 4) * 8 + j;
  float v = (NT == 1 && col >= 10) ? 0.f : w[col * 256 + k];
  short hi = f2bf(v);
  wfm[base + idx] = (term == 0) ? hi : f2bf(v - bf2f(hi));
}

// ---------------------------------------------------------------------------
// K1: per-sample A/B taps via bf16 MFMA + fused pairwise relu-pool.
// (unchanged from round 2 — passed at absmax 7.8e-3, est. ~5-7us)
// ---------------------------------------------------------------------------
__global__ __launch_bounds__(256) void conv_pairs_mfma(
    const float* __restrict__ x,    // (1024, 25*64)
    const short* __restrict__ wb,   // (2, 256, 64) bf16
    const float* __restrict__ cb,   // (256)
    float* __restrict__ h)          // (1024, 256)
{
  __shared__ short xs[2][32][72];
  __shared__ float ab[2][NOBJ][260];
  const int t = threadIdx.x;
  const int lane = t & 63;
  const int wv = t >> 6;
  const int r = lane & 15;
  const int g = lane >> 4;
  const int n0 = blockIdx.x * 2;

  bf16x8 Wf[2][4][2];  // [tap][ntile][kstep]
#pragma unroll
  for (int tap = 0; tap < 2; ++tap)
#pragma unroll
    for (int ntl = 0; ntl < 4; ++ntl)
#pragma unroll
      for (int ks = 0; ks < 2; ++ks) {
        int ch = wv * 64 + ntl * 16 + r;
        Wf[tap][ntl][ks] = *reinterpret_cast<const bf16x8*>(
            wb + tap * 16384 + ch * 64 + ks * 32 + g * 8);
      }

  float cbv[4];
#pragma unroll
  for (int ntl = 0; ntl < 4; ++ntl) cbv[ntl] = cb[wv * 64 + ntl * 16 + r];

  for (int s = 0; s < 2; ++s) {
    const float4* xg = reinterpret_cast<const float4*>(x + (size_t)(n0 + s) * (NOBJ * 64));
    for (int i = t; i < 400; i += 256) {
      float4 v = xg[i];
      s16x4 p;
      p.x = f2bf(v.x); p.y = f2bf(v.y); p.z = f2bf(v.z); p.w = f2bf(v.w);
      *reinterpret_cast<s16x4*>(&xs[s][i >> 4][(i & 15) * 4]) = p;
    }
  }
  __syncthreads();

  for (int s = 0; s < 2; ++s) {
    bf16x8 Xf[2][2];
#pragma unroll
    for (int mt = 0; mt < 2; ++mt)
#pragma unroll
      for (int ks = 0; ks < 2; ++ks)
        Xf[mt][ks] = *reinterpret_cast<const bf16x8*>(&xs[s][mt * 16 + r][ks * 32 + g * 8]);

    f32x4 acc[2][2][4];
#pragma unroll
    for (int tap = 0; tap < 2; ++tap)
#pragma unroll
      for (int mt = 0; mt < 2; ++mt)
#pragma unroll
        for (int ntl = 0; ntl < 4; ++ntl) {
          f32x4 z = {0.f, 0.f, 0.f, 0.f};
          acc[tap][mt][ntl] = z;
        }

#pragma unroll
    for (int tap = 0; tap < 2; ++tap)
#pragma unroll
      for (int mt = 0; mt < 2; ++mt)
#pragma unroll
        for (int ntl = 0; ntl < 4; ++ntl)
#pragma unroll
          for (int ks = 0; ks < 2; ++ks)
            acc[tap][mt][ntl] = __builtin_amdgcn_mfma_f32_16x16x32_bf16(
                Xf[mt][ks], Wf[tap][ntl][ks], acc[tap][mt][ntl], 0, 0, 0);

#pragma unroll
    for (int tap = 0; tap < 2; ++tap)
#pragma unroll
      for (int mt = 0; mt < 2; ++mt)
#pragma unroll
        for (int ntl = 0; ntl < 4; ++ntl) {
          const int ch = wv * 64 + ntl * 16 + r;
          const int row0 = mt * 16 + g * 4;
          const float badd = (tap == 0) ? cbv[ntl] : 0.f;
#pragma unroll
          for (int q = 0; q < 4; ++q)
            if (row0 + q < NOBJ) ab[tap][row0 + q][ch] = acc[tap][mt][ntl][q] + badd;
        }
    __syncthreads();

    float A[NOBJ], Bv[NOBJ];
#pragma unroll
    for (int i = 0; i < NOBJ; ++i) { A[i] = ab[0][i][t]; Bv[i] = ab[1][i][t]; }
    float hacc = 0.f;
#pragma unroll
    for (int d = 1; d < NOBJ; ++d) {
      float sd = 0.f;
#pragma unroll
      for (int i = 0; i + d < NOBJ; ++i) sd += fmaxf(A[i] + Bv[i + d], 0.f);
      hacc += sd * (1.0f / (float)(NOBJ - d));
    }
    h[(size_t)(n0 + s) * D0 + t] = hacc * (1.0f / (float)(NOBJ - 1));
    __syncthreads();
  }
}

// ---------------------------------------------------------------------------
// K2: fused 3-layer MLP via bf16 MFMA, hi/lo split on BOTH operands
// (acc += Hhi*Whi + Hhi*Wlo + Hlo*Whi; dropped lo*lo term ~2^-16 rel).
// 64 blocks x 256 threads; block owns 16 rows; wave wv owns cols [64wv,64wv+64).
// H ping-pongs in LDS as hi/lo bf16, pitch 264 shorts (reads run at the
// 1024B/instr LDS floor; all 32 banks busy). W streamed fragment-linear
// from L2 (coalesced dwordx4). Layer 3 (N=10, zero-padded W) on wave 0.
// ---------------------------------------------------------------------------
__global__ __launch_bounds__(256) void mlp_mfma(
    const float* __restrict__ h,    // (1024, 256) f32
    const short* __restrict__ wf,   // fragment-linear hi/lo bf16 weights
    const float* __restrict__ b1, const float* __restrict__ b2,
    const float* __restrict__ b3,
    float* __restrict__ out)        // (1024, 10)
{
  __shared__ short H[2][2][16][264];  // [pingpong][hi/lo][row][k] 33.8KB
  const int t = threadIdx.x, lane = t & 63, wv = t >> 6;
  const int r = lane & 15, g = lane >> 4;
  const int m0 = blockIdx.x * 16;

  for (int i = t; i < 4096; i += 256) {
    const int row = i >> 8, k = i & 255;
    const float v = h[(size_t)(m0 + row) * 256 + k];
    const short hi = f2bf(v);
    H[0][0][row][k] = hi;
    H[0][1][row][k] = f2bf(v - bf2f(hi));
  }
  __syncthreads();

  int pp = 0;
  const float* bias[2] = {b1, b2};
#pragma unroll
  for (int L = 0; L < 2; ++L) {
    const short* wl = wf + L * 131072;
    f32x4 acc[4];
#pragma unroll
    for (int ntl = 0; ntl < 4; ++ntl) {
      const float bv = bias[L][wv * 64 + ntl * 16 + r];
      f32x4 a = {bv, bv, bv, bv};
      acc[ntl] = a;
    }
#pragma unroll
    for (int ks = 0; ks < 8; ++ks) {
      const bf16x8 ahi = *reinterpret_cast<const bf16x8*>(&H[pp][0][r][ks * 32 + g * 8]);
      const bf16x8 alo = *reinterpret_cast<const bf16x8*>(&H[pp][1][r][ks * 32 + g * 8]);
#pragma unroll
      for (int ntl = 0; ntl < 4; ++ntl) {
        const int nt = wv * 4 + ntl;
        const short* pb = wl + ((nt * 8 + ks) << 9) + lane * 8;
        const bf16x8 bhi = *reinterpret_cast<const bf16x8*>(pb);
        const bf16x8 blo = *reinterpret_cast<const bf16x8*>(pb + 65536);
        acc[ntl] = __builtin_amdgcn_mfma_f32_16x16x32_bf16(ahi, bhi, acc[ntl], 0, 0, 0);
        acc[ntl] = __builtin_amdgcn_mfma_f32_16x16x32_bf16(ahi, blo, acc[ntl], 0, 0, 0);
        acc[ntl] = __builtin_amdgcn_mfma_f32_16x16x32_bf16(alo, bhi, acc[ntl], 0, 0, 0);
      }
    }
    // writeback relu(acc) as hi/lo into the other buffer
#pragma unroll
    for (int ntl = 0; ntl < 4; ++ntl) {
      const int col = wv * 64 + ntl * 16 + r;
#pragma unroll
      for (int q = 0; q < 4; ++q) {
        const float v = fmaxf(acc[ntl][q], 0.f);
        const int row = 4 * g + q;
        const short hi = f2bf(v);
        H[pp ^ 1][0][row][col] = hi;
        H[pp ^ 1][1][row][col] = f2bf(v - bf2f(hi));
      }
    }
    __syncthreads();
    pp ^= 1;
  }

  // layer 3: one 16x16 tile (cols 10..15 are zero-padded W), wave 0 only
  if (wv == 0) {
    const float bv = (r < 10) ? b3[r] : 0.f;
    f32x4 acc = {bv, bv, bv, bv};
#pragma unroll
    for (int ks = 0; ks < 8; ++ks) {
      const bf16x8 ahi = *reinterpret_cast<const bf16x8*>(&H[pp][0][r][ks * 32 + g * 8]);
      const bf16x8 alo = *reinterpret_cast<const bf16x8*>(&H[pp][1][r][ks * 32 + g * 8]);
      const short* pb = wf + 262144 + (ks << 9) + lane * 8;
      const bf16x8 bhi = *reinterpret_cast<const bf16x8*>(pb);
      const bf16x8 blo = *reinterpret_cast<const bf16x8*>(pb + 4096);
      acc = __builtin_amdgcn_mfma_f32_16x16x32_bf16(ahi, bhi, acc, 0, 0, 0);
      acc = __builtin_amdgcn_mfma_f32_16x16x32_bf16(ahi, blo, acc, 0, 0, 0);
      acc = __builtin_amdgcn_mfma_f32_16x16x32_bf16(alo, bhi, acc, 0, 0, 0);
    }
    if (r < 10) {
#pragma unroll
      for (int q = 0; q < 4; ++q)
        out[(size_t)(m0 + 4 * g + q) * 10 + r] = acc[q];
    }
  }
}

extern "C" void kernel_launch(void* const* d_in, const int* in_sizes, int n_in,
                              void* d_out, int out_size, void* d_ws, size_t ws_size,
                              hipStream_t stream) {
  const float* x   = (const float*)d_in[0];
  const float* cw0 = (const float*)d_in[1];
  const float* cw1 = (const float*)d_in[2];
  const float* cb  = (const float*)d_in[3];
  const float* w1  = (const float*)d_in[4];
  const float* b1  = (const float*)d_in[5];
  const float* w2  = (const float*)d_in[6];
  const float* b2  = (const float*)d_in[7];
  const float* w3  = (const float*)d_in[8];
  const float* b3  = (const float*)d_in[9];
  float* out = (float*)d_out;

  float* h   = (float*)d_ws;                         // 1 MB
  short* wbc = (short*)((char*)d_ws + (1 << 20));    // 64 KB conv taps bf16
  short* wfm = wbc + 32768;                          // 528 KB MLP frag weights

  prep_kernel<<<1184, 256, 0, stream>>>(cw0, cw1, w1, w2, w3, wbc, wfm);
  conv_pairs_mfma<<<512, 256, 0, stream>>>(x, wbc, cb, h);
  mlp_mfma<<<64, 256, 0, stream>>>(h, wfm, b1, b2, b3, out);
}

// Round 4
// 38.846 us; speedup vs baseline: 1.3194x; 1.3194x over previous
//
#include <hip/hip_runtime.h>
#include <hip/hip_bf16.h>

#define NOBJ 25
#define D0 256

typedef short bf16x8 __attribute__((ext_vector_type(8)));
typedef short s16x4 __attribute__((ext_vector_type(4)));
typedef float f32x4 __attribute__((ext_vector_type(4)));

__device__ __forceinline__ short f2bf(float f) {
  __hip_bfloat16 b = __float2bfloat16(f);  // RTN
  return *reinterpret_cast<short*>(&b);
}
__device__ __forceinline__ float bf2f(short s) {
  unsigned u = ((unsigned)(unsigned short)s) << 16;
  return __uint_as_float(u);
}

// ---------------------------------------------------------------------------
// prep: (a) conv taps -> bf16 (2,256,64); (b) MLP weights -> hi/lo bf16 in
// fragment-linear layout. All index math uses compile-time-constant divisors.
// Layout per layer L in {0,1}: [term(hi/lo)][nt][ks][lane][j], 131072 shorts.
// Layer 3 at +262144: [term][ks][lane][j], cols >= 10 zero-padded, 8192 shorts.
// value = w[(nt*16 + (lane&15)) * 256 + ks*32 + (lane>>4)*8 + j]
// ---------------------------------------------------------------------------
__global__ __launch_bounds__(256) void prep_kernel(
    const float* __restrict__ cw0, const float* __restrict__ cw1,
    const float* __restrict__ w1, const float* __restrict__ w2,
    const float* __restrict__ w3,
    short* __restrict__ wbc, short* __restrict__ wfm) {
  int i = blockIdx.x * 256 + threadIdx.x;
  if (i < 32768) {
    float v = (i < 16384) ? cw0[i] : cw1[i - 16384];
    wbc[i] = f2bf(v);
    return;
  }
  const int j = i - 32768;  // 0 .. 270335
  const float* w; int term, f, nt;
  if (j < 262144) {
    w = (j >> 17) ? w2 : w1;
    const int idx = j & 131071;
    term = idx >> 16;
    f = idx & 65535;
    nt = f >> 12;
  } else {
    w = w3;
    const int idx = j - 262144;  // 0..8191
    term = idx >> 12;
    f = idx & 4095;
    nt = 0;
  }
  const int ks = (f >> 9) & 7;
  const int l  = (f >> 3) & 63;
  const int jj = f & 7;
  const int col = nt * 16 + (l & 15);
  const int k   = ks * 32 + (l >> 4) * 8 + jj;
  float v = (w == w3 && col >= 10) ? 0.f : w[col * 256 + k];
  short hi = f2bf(v);
  wfm[j] = (term == 0) ? hi : f2bf(v - bf2f(hi));
}

// ---------------------------------------------------------------------------
// K1: per-sample A/B taps via bf16 MFMA + fused pairwise relu-pool.
// (byte-identical to rounds 2/3 — known-good, ~3-4us by model)
// ---------------------------------------------------------------------------
__global__ __launch_bounds__(256) void conv_pairs_mfma(
    const float* __restrict__ x,    // (1024, 25*64)
    const short* __restrict__ wb,   // (2, 256, 64) bf16
    const float* __restrict__ cb,   // (256)
    float* __restrict__ h)          // (1024, 256)
{
  __shared__ short xs[2][32][72];
  __shared__ float ab[2][NOBJ][260];
  const int t = threadIdx.x;
  const int lane = t & 63;
  const int wv = t >> 6;
  const int r = lane & 15;
  const int g = lane >> 4;
  const int n0 = blockIdx.x * 2;

  bf16x8 Wf[2][4][2];  // [tap][ntile][kstep]
#pragma unroll
  for (int tap = 0; tap < 2; ++tap)
#pragma unroll
    for (int ntl = 0; ntl < 4; ++ntl)
#pragma unroll
      for (int ks = 0; ks < 2; ++ks) {
        int ch = wv * 64 + ntl * 16 + r;
        Wf[tap][ntl][ks] = *reinterpret_cast<const bf16x8*>(
            wb + tap * 16384 + ch * 64 + ks * 32 + g * 8);
      }

  float cbv[4];
#pragma unroll
  for (int ntl = 0; ntl < 4; ++ntl) cbv[ntl] = cb[wv * 64 + ntl * 16 + r];

  for (int s = 0; s < 2; ++s) {
    const float4* xg = reinterpret_cast<const float4*>(x + (size_t)(n0 + s) * (NOBJ * 64));
    for (int i = t; i < 400; i += 256) {
      float4 v = xg[i];
      s16x4 p;
      p.x = f2bf(v.x); p.y = f2bf(v.y); p.z = f2bf(v.z); p.w = f2bf(v.w);
      *reinterpret_cast<s16x4*>(&xs[s][i >> 4][(i & 15) * 4]) = p;
    }
  }
  __syncthreads();

  for (int s = 0; s < 2; ++s) {
    bf16x8 Xf[2][2];
#pragma unroll
    for (int mt = 0; mt < 2; ++mt)
#pragma unroll
      for (int ks = 0; ks < 2; ++ks)
        Xf[mt][ks] = *reinterpret_cast<const bf16x8*>(&xs[s][mt * 16 + r][ks * 32 + g * 8]);

    f32x4 acc[2][2][4];
#pragma unroll
    for (int tap = 0; tap < 2; ++tap)
#pragma unroll
      for (int mt = 0; mt < 2; ++mt)
#pragma unroll
        for (int ntl = 0; ntl < 4; ++ntl) {
          f32x4 z = {0.f, 0.f, 0.f, 0.f};
          acc[tap][mt][ntl] = z;
        }

#pragma unroll
    for (int tap = 0; tap < 2; ++tap)
#pragma unroll
      for (int mt = 0; mt < 2; ++mt)
#pragma unroll
        for (int ntl = 0; ntl < 4; ++ntl)
#pragma unroll
          for (int ks = 0; ks < 2; ++ks)
            acc[tap][mt][ntl] = __builtin_amdgcn_mfma_f32_16x16x32_bf16(
                Xf[mt][ks], Wf[tap][ntl][ks], acc[tap][mt][ntl], 0, 0, 0);

#pragma unroll
    for (int tap = 0; tap < 2; ++tap)
#pragma unroll
      for (int mt = 0; mt < 2; ++mt)
#pragma unroll
        for (int ntl = 0; ntl < 4; ++ntl) {
          const int ch = wv * 64 + ntl * 16 + r;
          const int row0 = mt * 16 + g * 4;
          const float badd = (tap == 0) ? cbv[ntl] : 0.f;
#pragma unroll
          for (int q = 0; q < 4; ++q)
            if (row0 + q < NOBJ) ab[tap][row0 + q][ch] = acc[tap][mt][ntl][q] + badd;
        }
    __syncthreads();

    float A[NOBJ], Bv[NOBJ];
#pragma unroll
    for (int i = 0; i < NOBJ; ++i) { A[i] = ab[0][i][t]; Bv[i] = ab[1][i][t]; }
    float hacc = 0.f;
#pragma unroll
    for (int d = 1; d < NOBJ; ++d) {
      float sd = 0.f;
#pragma unroll
      for (int i = 0; i + d < NOBJ; ++i) sd += fmaxf(A[i] + Bv[i + d], 0.f);
      hacc += sd * (1.0f / (float)(NOBJ - d));
    }
    h[(size_t)(n0 + s) * D0 + t] = hacc * (1.0f / (float)(NOBJ - 1));
    __syncthreads();
  }
}

// ---------------------------------------------------------------------------
// K2: fused 3-layer MLP, bf16 MFMA with hi/lo split (3 terms, lo*lo dropped).
// 64 blocks x 256 threads (1 wave/SIMD -> latency hiding must be ILP):
// per layer, ALL 32 hi-B fragments are bulk-loaded before any MFMA consumes
// them (one amortized L2 round-trip), then the 32 lo-B frags reuse the freed
// registers. Peak ~250 VGPR, all statically indexed (no scratch).
// ---------------------------------------------------------------------------
__global__ __launch_bounds__(256) void mlp_mfma(
    const float* __restrict__ h,    // (1024, 256) f32
    const short* __restrict__ wf,   // fragment-linear hi/lo bf16 weights
    const float* __restrict__ b1, const float* __restrict__ b2,
    const float* __restrict__ b3,
    float* __restrict__ out)        // (1024, 10)
{
  __shared__ short H[2][2][16][264];  // [pingpong][hi/lo][row][k] 33.8KB
  const int t = threadIdx.x, lane = t & 63, wv = t >> 6;
  const int r = lane & 15, g = lane >> 4;
  const int m0 = blockIdx.x * 16;

  for (int i = t; i < 4096; i += 256) {
    const int row = i >> 8, k = i & 255;
    const float v = h[(size_t)(m0 + row) * 256 + k];
    const short hi = f2bf(v);
    H[0][0][row][k] = hi;
    H[0][1][row][k] = f2bf(v - bf2f(hi));
  }
  __syncthreads();

  int pp = 0;
  const float* bias[2] = {b1, b2};
#pragma unroll
  for (int L = 0; L < 2; ++L) {
    const short* wl = wf + L * 131072;

    // A-fragments (LDS), both terms
    bf16x8 ahi[8], alo[8];
#pragma unroll
    for (int ks = 0; ks < 8; ++ks) {
      ahi[ks] = *reinterpret_cast<const bf16x8*>(&H[pp][0][r][ks * 32 + g * 8]);
      alo[ks] = *reinterpret_cast<const bf16x8*>(&H[pp][1][r][ks * 32 + g * 8]);
    }

    f32x4 acc[4];
#pragma unroll
    for (int ntl = 0; ntl < 4; ++ntl) {
      const float bv = bias[L][wv * 64 + ntl * 16 + r];
      f32x4 a = {bv, bv, bv, bv};
      acc[ntl] = a;
    }

    // ---- hi-B bulk load, then 64 MFMAs (ahi*bhi + alo*bhi)
    {
      bf16x8 bh[4][8];
#pragma unroll
      for (int ntl = 0; ntl < 4; ++ntl)
#pragma unroll
        for (int ks = 0; ks < 8; ++ks)
          bh[ntl][ks] = *reinterpret_cast<const bf16x8*>(
              wl + (((wv * 4 + ntl) * 8 + ks) << 9) + lane * 8);
#pragma unroll
      for (int ks = 0; ks < 8; ++ks)
#pragma unroll
        for (int ntl = 0; ntl < 4; ++ntl) {
          acc[ntl] = __builtin_amdgcn_mfma_f32_16x16x32_bf16(ahi[ks], bh[ntl][ks], acc[ntl], 0, 0, 0);
          acc[ntl] = __builtin_amdgcn_mfma_f32_16x16x32_bf16(alo[ks], bh[ntl][ks], acc[ntl], 0, 0, 0);
        }
    }
    // ---- lo-B bulk load, then 32 MFMAs (ahi*blo)
    {
      bf16x8 bl[4][8];
#pragma unroll
      for (int ntl = 0; ntl < 4; ++ntl)
#pragma unroll
        for (int ks = 0; ks < 8; ++ks)
          bl[ntl][ks] = *reinterpret_cast<const bf16x8*>(
              wl + 65536 + (((wv * 4 + ntl) * 8 + ks) << 9) + lane * 8);
#pragma unroll
      for (int ks = 0; ks < 8; ++ks)
#pragma unroll
        for (int ntl = 0; ntl < 4; ++ntl)
          acc[ntl] = __builtin_amdgcn_mfma_f32_16x16x32_bf16(ahi[ks], bl[ntl][ks], acc[ntl], 0, 0, 0);
    }

    // writeback relu(acc) as hi/lo into the other buffer
#pragma unroll
    for (int ntl = 0; ntl < 4; ++ntl) {
      const int col = wv * 64 + ntl * 16 + r;
#pragma unroll
      for (int q = 0; q < 4; ++q) {
        const float v = fmaxf(acc[ntl][q], 0.f);
        const int row = 4 * g + q;
        const short hi = f2bf(v);
        H[pp ^ 1][0][row][col] = hi;
        H[pp ^ 1][1][row][col] = f2bf(v - bf2f(hi));
      }
    }
    __syncthreads();
    pp ^= 1;
  }

  // layer 3: one 16x16 tile (cols 10..15 zero-padded), wave 0 only
  if (wv == 0) {
    const float bv = (r < 10) ? b3[r] : 0.f;
    f32x4 acc = {bv, bv, bv, bv};
    bf16x8 ahi[8], alo[8], bh[8], bl[8];
#pragma unroll
    for (int ks = 0; ks < 8; ++ks) {
      ahi[ks] = *reinterpret_cast<const bf16x8*>(&H[pp][0][r][ks * 32 + g * 8]);
      alo[ks] = *reinterpret_cast<const bf16x8*>(&H[pp][1][r][ks * 32 + g * 8]);
      bh[ks] = *reinterpret_cast<const bf16x8*>(wf + 262144 + (ks << 9) + lane * 8);
      bl[ks] = *reinterpret_cast<const bf16x8*>(wf + 262144 + 4096 + (ks << 9) + lane * 8);
    }
#pragma unroll
    for (int ks = 0; ks < 8; ++ks) {
      acc = __builtin_amdgcn_mfma_f32_16x16x32_bf16(ahi[ks], bh[ks], acc, 0, 0, 0);
      acc = __builtin_amdgcn_mfma_f32_16x16x32_bf16(alo[ks], bh[ks], acc, 0, 0, 0);
      acc = __builtin_amdgcn_mfma_f32_16x16x32_bf16(ahi[ks], bl[ks], acc, 0, 0, 0);
    }
    if (r < 10) {
#pragma unroll
      for (int q = 0; q < 4; ++q)
        out[(size_t)(m0 + 4 * g + q) * 10 + r] = acc[q];
    }
  }
}

extern "C" void kernel_launch(void* const* d_in, const int* in_sizes, int n_in,
                              void* d_out, int out_size, void* d_ws, size_t ws_size,
                              hipStream_t stream) {
  const float* x   = (const float*)d_in[0];
  const float* cw0 = (const float*)d_in[1];
  const float* cw1 = (const float*)d_in[2];
  const float* cb  = (const float*)d_in[3];
  const float* w1  = (const float*)d_in[4];
  const float* b1  = (const float*)d_in[5];
  const float* w2  = (const float*)d_in[6];
  const float* b2  = (const float*)d_in[7];
  const float* w3  = (const float*)d_in[8];
  const float* b3  = (const float*)d_in[9];
  float* out = (float*)d_out;

  float* h   = (float*)d_ws;                         // 1 MB
  short* wbc = (short*)((char*)d_ws + (1 << 20));    // 64 KB conv taps bf16
  short* wfm = wbc + 32768;                          // 528+16 KB MLP frag weights

  prep_kernel<<<1184, 256, 0, stream>>>(cw0, cw1, w1, w2, w3, wbc, wfm);
  conv_pairs_mfma<<<512, 256, 0, stream>>>(x, wbc, cb, h);
  mlp_mfma<<<64, 256, 0, stream>>>(h, wfm, b1, b2, b3, out);
}

// Round 5
// 34.989 us; speedup vs baseline: 1.4649x; 1.1102x over previous
//
#include <hip/hip_runtime.h>
#include <hip/hip_bf16.h>

#define NOBJ 25

typedef short bf16x8 __attribute__((ext_vector_type(8)));
typedef short s16x4 __attribute__((ext_vector_type(4)));
typedef float f32x4 __attribute__((ext_vector_type(4)));

__device__ __forceinline__ short f2bf(float f) {
  __hip_bfloat16 b = __float2bfloat16(f);  // RTN
  return *reinterpret_cast<short*>(&b);
}
__device__ __forceinline__ float bf2f(short s) {
  unsigned u = ((unsigned)(unsigned short)s) << 16;
  return __uint_as_float(u);
}

// ---------------------------------------------------------------------------
// K1: blocks 0..511  : conv taps via bf16 MFMA (inline f32->bf16 W-frag
//                      conversion) + wave-local pairwise relu-pool, 2 samples.
//     blocks 512..639: MLP weight prep (hi/lo bf16, fragment-linear) --
//                      runs concurrently, hidden under the conv blocks.
// Wave-locality: wave wv computes channels [64wv,64wv+64) and its pairwise
// threads read exactly those -> ab is per-wave scratch, NO barrier in the
// sample loop (LDS deps within a wave are ordered by lgkmcnt). Single
// __syncthreads after cooperative xs staging.
// ab banks: scatter lanes (r,g) -> bank r+16((g+ntl)&1)+4q : 2-way (free);
// pairwise reads: consecutive lanes -> consecutive words : 2-way (free).
// ---------------------------------------------------------------------------
__global__ __launch_bounds__(256) void conv_prep_kernel(
    const float* __restrict__ x,    // (1024, 25*64)
    const float* __restrict__ cw0,  // (256, 64)
    const float* __restrict__ cw1,  // (256, 64)
    const float* __restrict__ cb,   // (256)
    const float* __restrict__ w1, const float* __restrict__ w2,
    const float* __restrict__ w3,
    float* __restrict__ h,          // (1024, 256)
    short* __restrict__ wfm)        // 270336 shorts, fragment-linear hi/lo
{
  __shared__ short xs[2][32][72];        // 9216 B
  __shared__ float ab[4][2][NOBJ][68];   // 54400 B  (per-wave scratch)

  if (blockIdx.x >= 512) {
    // ---- MLP weight prep branch (uniform per block) ----
    // Layout per layer L in {0,1} at L*131072: [term][nt][ks][lane][j];
    // layer 3 at 262144: [term][ks][lane][j], cols>=10 zero-padded.
    // value = w[(nt*16+(lane&15))*256 + ks*32 + (lane>>4)*8 + j]
    for (int j = (blockIdx.x - 512) * 256 + threadIdx.x; j < 270336; j += 128 * 256) {
      const float* w; int term, f, nt;
      bool isw3 = (j >= 262144);
      if (!isw3) {
        w = (j >> 17) ? w2 : w1;
        const int idx = j & 131071;
        term = idx >> 16; f = idx & 65535; nt = f >> 12;
      } else {
        w = w3;
        const int idx = j - 262144;  // 0..8191
        term = idx >> 12; f = idx & 4095; nt = 0;
      }
      const int ks = (f >> 9) & 7;
      const int l  = (f >> 3) & 63;
      const int jj = f & 7;
      const int col = nt * 16 + (l & 15);
      const int k   = ks * 32 + (l >> 4) * 8 + jj;
      float v = (isw3 && col >= 10) ? 0.f : w[col * 256 + k];
      short hi = f2bf(v);
      wfm[j] = (term == 0) ? hi : f2bf(v - bf2f(hi));
    }
    return;
  }

  // ---- conv branch ----
  const int t = threadIdx.x;
  const int lane = t & 63;
  const int wv = t >> 6;
  const int r = lane & 15;
  const int g = lane >> 4;
  const int n0 = blockIdx.x * 2;

  // W fragments for both taps, converted inline from f32 (one-time).
  bf16x8 Wf[2][4][2];  // [tap][ntile][kstep]
#pragma unroll
  for (int tap = 0; tap < 2; ++tap) {
    const float* wsrc = tap ? cw1 : cw0;
#pragma unroll
    for (int ntl = 0; ntl < 4; ++ntl)
#pragma unroll
      for (int ks = 0; ks < 2; ++ks) {
        const int ch = wv * 64 + ntl * 16 + r;
        const float* p = wsrc + ch * 64 + ks * 32 + g * 8;
        const float4 a = *reinterpret_cast<const float4*>(p);
        const float4 b = *reinterpret_cast<const float4*>(p + 4);
        bf16x8 fr;
        fr[0] = f2bf(a.x); fr[1] = f2bf(a.y); fr[2] = f2bf(a.z); fr[3] = f2bf(a.w);
        fr[4] = f2bf(b.x); fr[5] = f2bf(b.y); fr[6] = f2bf(b.z); fr[7] = f2bf(b.w);
        Wf[tap][ntl][ks] = fr;
      }
  }

  float cbv[4];
#pragma unroll
  for (int ntl = 0; ntl < 4; ++ntl) cbv[ntl] = cb[wv * 64 + ntl * 16 + r];

  // cooperative x staging (both samples) -> single barrier
  for (int s = 0; s < 2; ++s) {
    const float4* xg = reinterpret_cast<const float4*>(x + (size_t)(n0 + s) * (NOBJ * 64));
    for (int i = t; i < 400; i += 256) {
      float4 v = xg[i];
      s16x4 p;
      p.x = f2bf(v.x); p.y = f2bf(v.y); p.z = f2bf(v.z); p.w = f2bf(v.w);
      *reinterpret_cast<s16x4*>(&xs[s][i >> 4][(i & 15) * 4]) = p;
    }
  }
  __syncthreads();

  for (int s = 0; s < 2; ++s) {
    bf16x8 Xf[2][2];  // [mtile][kstep]; rows 25..31 garbage, never read out
#pragma unroll
    for (int mt = 0; mt < 2; ++mt)
#pragma unroll
      for (int ks = 0; ks < 2; ++ks)
        Xf[mt][ks] = *reinterpret_cast<const bf16x8*>(&xs[s][mt * 16 + r][ks * 32 + g * 8]);

    f32x4 acc[2][2][4];  // [tap][mtile][ntile]
#pragma unroll
    for (int tap = 0; tap < 2; ++tap)
#pragma unroll
      for (int mt = 0; mt < 2; ++mt)
#pragma unroll
        for (int ntl = 0; ntl < 4; ++ntl) {
          f32x4 z = {0.f, 0.f, 0.f, 0.f};
          acc[tap][mt][ntl] = z;
        }

#pragma unroll
    for (int tap = 0; tap < 2; ++tap)
#pragma unroll
      for (int mt = 0; mt < 2; ++mt)
#pragma unroll
        for (int ntl = 0; ntl < 4; ++ntl)
#pragma unroll
          for (int ks = 0; ks < 2; ++ks)
            acc[tap][mt][ntl] = __builtin_amdgcn_mfma_f32_16x16x32_bf16(
                Xf[mt][ks], Wf[tap][ntl][ks], acc[tap][mt][ntl], 0, 0, 0);

    // wave-local scatter (D: col=lane&15 -> channel, row=4*(lane>>4)+q -> object)
#pragma unroll
    for (int tap = 0; tap < 2; ++tap)
#pragma unroll
      for (int mt = 0; mt < 2; ++mt)
#pragma unroll
        for (int ntl = 0; ntl < 4; ++ntl) {
          const int cl = ntl * 16 + r;
          const int row0 = mt * 16 + g * 4;
          const float badd = (tap == 0) ? cbv[ntl] : 0.f;
#pragma unroll
          for (int q = 0; q < 4; ++q)
            if (row0 + q < NOBJ) ab[wv][tap][row0 + q][cl] = acc[tap][mt][ntl][q] + badd;
        }
    // no barrier: same-wave LDS RAW is ordered by lgkmcnt

    float A[NOBJ], Bv[NOBJ];
#pragma unroll
    for (int i = 0; i < NOBJ; ++i) { A[i] = ab[wv][0][i][lane]; Bv[i] = ab[wv][1][i][lane]; }
    float hacc = 0.f;
#pragma unroll
    for (int d = 1; d < NOBJ; ++d) {
      float sd = 0.f;
#pragma unroll
      for (int i = 0; i + d < NOBJ; ++i) sd += fmaxf(A[i] + Bv[i + d], 0.f);
      hacc += sd * (1.0f / (float)(NOBJ - d));
    }
    h[(size_t)(n0 + s) * 256 + t] = hacc * (1.0f / (float)(NOBJ - 1));
    // no barrier: ab is wave-private, next-sample writes follow this wave's reads
  }
}

// ---------------------------------------------------------------------------
// K2: fused 3-layer MLP, bf16 MFMA hi/lo split (3 terms). 64 blocks x 512
// threads (8 waves = 2/SIMD -> TLP hides the L2 bulk-loads). Wave wv owns
// cols [32wv, 32wv+32) (nt = wv*2+ntl). Per layer: bulk-load 16 hi-B frags,
// 32 MFMAs, bulk-load 16 lo-B frags, 16 MFMAs. H hi/lo ping-pong in LDS.
// ---------------------------------------------------------------------------
__global__ __launch_bounds__(512) void mlp_mfma(
    const float* __restrict__ h,    // (1024, 256) f32
    const short* __restrict__ wf,   // fragment-linear hi/lo bf16 weights
    const float* __restrict__ b1, const float* __restrict__ b2,
    const float* __restrict__ b3,
    float* __restrict__ out)        // (1024, 10)
{
  __shared__ short H[2][2][16][264];  // [pingpong][hi/lo][row][k] 33.8KB
  const int t = threadIdx.x, lane = t & 63, wv = t >> 6;
  const int r = lane & 15, g = lane >> 4;
  const int m0 = blockIdx.x * 16;

  for (int i = t; i < 4096; i += 512) {
    const int row = i >> 8, k = i & 255;
    const float v = h[(size_t)(m0 + row) * 256 + k];
    const short hi = f2bf(v);
    H[0][0][row][k] = hi;
    H[0][1][row][k] = f2bf(v - bf2f(hi));
  }
  __syncthreads();

  int pp = 0;
  const float* bias[2] = {b1, b2};
#pragma unroll
  for (int L = 0; L < 2; ++L) {
    const short* wl = wf + L * 131072;

    bf16x8 ahi[8], alo[8];
#pragma unroll
    for (int ks = 0; ks < 8; ++ks) {
      ahi[ks] = *reinterpret_cast<const bf16x8*>(&H[pp][0][r][ks * 32 + g * 8]);
      alo[ks] = *reinterpret_cast<const bf16x8*>(&H[pp][1][r][ks * 32 + g * 8]);
    }

    f32x4 acc[2];
#pragma unroll
    for (int ntl = 0; ntl < 2; ++ntl) {
      const float bv = bias[L][wv * 32 + ntl * 16 + r];
      f32x4 a = {bv, bv, bv, bv};
      acc[ntl] = a;
    }

    {  // hi-B bulk load, then 32 MFMAs
      bf16x8 bh[2][8];
#pragma unroll
      for (int ntl = 0; ntl < 2; ++ntl)
#pragma unroll
        for (int ks = 0; ks < 8; ++ks)
          bh[ntl][ks] = *reinterpret_cast<const bf16x8*>(
              wl + (((wv * 2 + ntl) * 8 + ks) << 9) + lane * 8);
#pragma unroll
      for (int ks = 0; ks < 8; ++ks)
#pragma unroll
        for (int ntl = 0; ntl < 2; ++ntl) {
          acc[ntl] = __builtin_amdgcn_mfma_f32_16x16x32_bf16(ahi[ks], bh[ntl][ks], acc[ntl], 0, 0, 0);
          acc[ntl] = __builtin_amdgcn_mfma_f32_16x16x32_bf16(alo[ks], bh[ntl][ks], acc[ntl], 0, 0, 0);
        }
    }
    {  // lo-B bulk load, then 16 MFMAs
      bf16x8 bl[2][8];
#pragma unroll
      for (int ntl = 0; ntl < 2; ++ntl)
#pragma unroll
        for (int ks = 0; ks < 8; ++ks)
          bl[ntl][ks] = *reinterpret_cast<const bf16x8*>(
              wl + 65536 + (((wv * 2 + ntl) * 8 + ks) << 9) + lane * 8);
#pragma unroll
      for (int ks = 0; ks < 8; ++ks)
#pragma unroll
        for (int ntl = 0; ntl < 2; ++ntl)
          acc[ntl] = __builtin_amdgcn_mfma_f32_16x16x32_bf16(ahi[ks], bl[ntl][ks], acc[ntl], 0, 0, 0);
    }

#pragma unroll
    for (int ntl = 0; ntl < 2; ++ntl) {
      const int col = wv * 32 + ntl * 16 + r;
#pragma unroll
      for (int q = 0; q < 4; ++q) {
        const float v = fmaxf(acc[ntl][q], 0.f);
        const int row = 4 * g + q;
        const short hi = f2bf(v);
        H[pp ^ 1][0][row][col] = hi;
        H[pp ^ 1][1][row][col] = f2bf(v - bf2f(hi));
      }
    }
    __syncthreads();
    pp ^= 1;
  }

  // layer 3: one 16x16 tile (cols 10..15 zero-padded), wave 0 only
  if (wv == 0) {
    const float bv = (r < 10) ? b3[r] : 0.f;
    f32x4 acc = {bv, bv, bv, bv};
    bf16x8 ahi[8], alo[8], bh[8], bl[8];
#pragma unroll
    for (int ks = 0; ks < 8; ++ks) {
      ahi[ks] = *reinterpret_cast<const bf16x8*>(&H[pp][0][r][ks * 32 + g * 8]);
      alo[ks] = *reinterpret_cast<const bf16x8*>(&H[pp][1][r][ks * 32 + g * 8]);
      bh[ks] = *reinterpret_cast<const bf16x8*>(wf + 262144 + (ks << 9) + lane * 8);
      bl[ks] = *reinterpret_cast<const bf16x8*>(wf + 262144 + 4096 + (ks << 9) + lane * 8);
    }
#pragma unroll
    for (int ks = 0; ks < 8; ++ks) {
      acc = __builtin_amdgcn_mfma_f32_16x16x32_bf16(ahi[ks], bh[ks], acc, 0, 0, 0);
      acc = __builtin_amdgcn_mfma_f32_16x16x32_bf16(alo[ks], bh[ks], acc, 0, 0, 0);
      acc = __builtin_amdgcn_mfma_f32_16x16x32_bf16(ahi[ks], bl[ks], acc, 0, 0, 0);
    }
    if (r < 10) {
#pragma unroll
      for (int q = 0; q < 4; ++q)
        out[(size_t)(m0 + 4 * g + q) * 10 + r] = acc[q];
    }
  }
}

extern "C" void kernel_launch(void* const* d_in, const int* in_sizes, int n_in,
                              void* d_out, int out_size, void* d_ws, size_t ws_size,
                              hipStream_t stream) {
  const float* x   = (const float*)d_in[0];
  const float* cw0 = (const float*)d_in[1];
  const float* cw1 = (const float*)d_in[2];
  const float* cb  = (const float*)d_in[3];
  const float* w1  = (const float*)d_in[4];
  const float* b1  = (const float*)d_in[5];
  const float* w2  = (const float*)d_in[6];
  const float* b2  = (const float*)d_in[7];
  const float* w3  = (const float*)d_in[8];
  const float* b3  = (const float*)d_in[9];
  float* out = (float*)d_out;

  float* h   = (float*)d_ws;                        // 1 MB: (1024,256) f32
  short* wfm = (short*)((char*)d_ws + (1 << 20));   // 540 KB: MLP frag weights

  conv_prep_kernel<<<640, 256, 0, stream>>>(x, cw0, cw1, cb, w1, w2, w3, h, wfm);
  mlp_mfma<<<64, 512, 0, stream>>>(h, wfm, b1, b2, b3, out);
}